// Round 16
// baseline (625.263 us; speedup 1.0000x reference)
//
#include <hip/hip_runtime.h>

typedef unsigned short u16;
typedef unsigned int u32;
typedef short v8s __attribute__((ext_vector_type(8)));
typedef float v4f __attribute__((ext_vector_type(4)));
typedef float v2f __attribute__((ext_vector_type(2)));

#define B_SZ 8
#define HH 32
#define WW 32
#define NN 1024          // H*W
#define M1 (B_SZ * NN)   // 8192 rows (one direction)
#define M4 (4 * M1)      // 32768 rows (all four directions)
#define NCHUNK 16
#define CLEN 64          // NCHUNK*CLEN = 1024
#define CTB 8            // conv t-rows per block

__device__ __forceinline__ float bf2f(u16 u) {
    u32 x = ((u32)u) << 16;
    return __builtin_bit_cast(float, x);
}
__device__ __forceinline__ u16 f2bf(float f) {
    u32 x = __builtin_bit_cast(u32, f);
    x = x + 0x7fffu + ((x >> 16) & 1u);
    return (u16)(x >> 16);
}
// single v_rcp_f32 (~1 ulp) instead of the precise-div sequence
__device__ __forceinline__ float rcp_(float x) { return __builtin_amdgcn_rcpf(x); }
__device__ __forceinline__ float sigmoidf_(float x) { return rcp_(1.f + __expf(-x)); }
__device__ __forceinline__ float ldf(const void* p, size_t i, int fin) {
    return fin ? ((const float*)p)[i] : bf2f(((const u16*)p)[i]);
}
// volatile variant: blocks LICM (used in the cold general scan path so its
// per-state A values don't get hoisted into 32 live registers)
__device__ __forceinline__ float ldf_v(const void* p, size_t i, int fin) {
    return fin ? ((volatile const float*)p)[i]
               : bf2f(((volatile const u16*)p)[i]);
}
__device__ __forceinline__ u16 ldbf(const void* p, size_t i, int fin) {
    return fin ? f2bf(((const float*)p)[i]) : ((const u16*)p)[i];
}
// async global->LDS, 16B per lane; LDS dest = wave-uniform base + lane*16
__device__ __forceinline__ void gload_lds16(const u16* g, u16* l) {
    __builtin_amdgcn_global_load_lds(
        (const __attribute__((address_space(1))) unsigned int*)g,
        (__attribute__((address_space(3))) unsigned int*)l, 16, 0, 0);
}
__device__ __forceinline__ int dirmap(int d, int t, const int* __restrict__ perm3) {
    if (d == 0) return t;
    if (d == 1) return (NN - 1) - t;
    if (d == 2) return (t & (HH - 1)) * WW + (t >> 5);
    return perm3[t];
}

// ---------------- setup: dtype sniffer + diagonal permutation (merged) ------
__global__ void setup_kernel(const u16* __restrict__ raw, int* __restrict__ flags,
                             int* __restrict__ perm, int* __restrict__ inv) {
    if (blockIdx.x == 0 && threadIdx.x == 0) {
        int ok = 0;
        for (int i = 0; i < 512; i++) {
            int e = (raw[i] >> 7) & 0xFF;
            ok += (e >= 100 && e <= 140) ? 1 : 0;
        }
        flags[0] = (ok < 460) ? 1 : 0;
    }
    int t = blockIdx.x * blockDim.x + threadIdx.x;
    if (t >= NN) return;
    int i = t / WW, j = t % WW;
    int off = j - i;
    int start = 0;
    for (int o = -(HH - 1); o < off; ++o) {
        int lo = (0 > -o) ? 0 : -o;
        int hi = (HH - 1 < WW - 1 - o) ? (HH - 1) : (WW - 1 - o);
        start += (hi - lo + 1);
    }
    int lo0 = (0 > -off) ? 0 : -off;
    int r = start + (i - lo0);
    perm[r] = t;
    inv[t] = r;
}

__global__ __launch_bounds__(256) void convert_bf(const void* __restrict__ src,
                                                  u16* __restrict__ dst,
                                                  const int* __restrict__ flags, int n) {
    int fin = flags[0];
    int i = blockIdx.x * 256 + threadIdx.x;
    if (i < n) dst[i] = ldbf(src, (size_t)i, fin);
}

__global__ __launch_bounds__(256) void zero_f32(float* __restrict__ p, int n) {
    int i = blockIdx.x * 256 + threadIdx.x;
    if (i < n) p[i] = 0.f;
}

// ---------------- batched weight transpose+pad: 4 weights, one dispatch -----
// grid (32, 130): y in [0,64) W_in(Nsrc=2048); [64,66) W_xproj(32);
// [66,98) W_outm(1024); [98,130) W_outpj(1024). All K=1024.
__global__ __launch_bounds__(256) void transpose_pad4(
        const void* __restrict__ s0, u16* __restrict__ d0,      // W_in
        const void* __restrict__ s1, u16* __restrict__ d1,      // W_xproj
        const void* __restrict__ s2, u16* __restrict__ d2,      // W_outm
        const void* __restrict__ s3, u16* __restrict__ d3,      // W_outpj
        const int* __restrict__ flags) {
    int fin = flags[0];
    const int K = 1024;
    int yb = blockIdx.y;
    const void* src;
    u16* dst;
    int Nsrc, n0;
    if (yb < 64)       { src = s0; dst = d0; Nsrc = 2048; n0 = yb * 32; }
    else if (yb < 66)  { src = s1; dst = d1; Nsrc = 32;   n0 = (yb - 64) * 32; }
    else if (yb < 98)  { src = s2; dst = d2; Nsrc = 1024; n0 = (yb - 66) * 32; }
    else               { src = s3; dst = d3; Nsrc = 1024; n0 = (yb - 98) * 32; }
    __shared__ u16 tile[32][33];
    int k0 = blockIdx.x * 32;
    int tx = threadIdx.x & 31, ty = threadIdx.x >> 5;
#pragma unroll
    for (int i = 0; i < 4; i++) {
        int k = k0 + ty + i * 8, n = n0 + tx;
        tile[ty + i * 8][tx] = (n < Nsrc) ? ldbf(src, (size_t)k * Nsrc + n, fin) : (u16)0;
    }
    __syncthreads();
#pragma unroll
    for (int i = 0; i < 4; i++) {
        int n = n0 + ty + i * 8, k = k0 + tx;
        dst[(size_t)n * K + k] = tile[tx][ty + i * 8];
    }
}

// ---------------- BMxBN MFMA GEMM, BK=64 (global_load_lds + XOR swizzle) ----
// C(MxN) = A(MxK) * Bt(NxK)^T. 256 thr = 4 waves (2x2); wave (WI*16)x(WJ*16).
// R14: K-step 64 — halves the vmcnt(0)+barrier drains per K-loop (verified:
// 640->614, bit-identical). 8-seg XOR swizzle for 128-B rows: phys seg p8 of
// row r holds logical p8^(r&7); reads phys=(kk*4+quad)^(l16&7).
// __launch_bounds__(256,4): cap unified regs at 128 — verified R9 (+1 wave).
// EM: 0 bf16 plain store; 1 split xz -> xi, silu(z) pre-activated (N=2048);
//     4 final out = vf + g*acc (aux0=vf raw, aux1=g); 5 fp32 plain store
//     (dtbc: WI=WJ=2, grid (512,1)).
template <int EM, int WI, int WJ>
__global__ __launch_bounds__(256, 4) void gemm128(const u16* __restrict__ A,
                                                  const u16* __restrict__ Bt,
                                                  void* __restrict__ out0,
                                                  void* __restrict__ out1,
                                                  int M, int N, int K,
                                                  const int* __restrict__ flags,
                                                  const void* __restrict__ aux0,
                                                  const float* __restrict__ aux1) {
    constexpr int BM = WI * 32;
    constexpr int BN = WJ * 32;
    int fin = flags[0];
    __shared__ __align__(16) u16 As[BM][64];
    __shared__ __align__(16) u16 Bs[BN][64];
    int tid = threadIdx.x;
    int wave = tid >> 6, lane = tid & 63, quad = lane >> 4, l16 = lane & 15;
    int wm = wave >> 1, wn = wave & 1;
    int m0 = blockIdx.x * BM, n0 = blockIdx.y * BN;
    int r8 = tid >> 3, p8 = tid & 7;          // 32 rows x 8 segs per gload call
    int sw = (p8 ^ (r8 & 7)) * 8;             // inverse-swizzled src seg (elems)

    const u16* aBase = A  + (size_t)(m0 + r8) * K + sw;
    const u16* bBase = Bt + (size_t)(n0 + r8) * K + sw;
    size_t rstride = (size_t)32 * K;          // 32 rows per gload call

    v4f acc[WI][WJ];
#pragma unroll
    for (int i = 0; i < WI; i++)
#pragma unroll
        for (int j = 0; j < WJ; j++) acc[i][j] = (v4f){0.f, 0.f, 0.f, 0.f};

    int seg0 = ((0 + quad) ^ (l16 & 7)) * 8;  // kk=0 phys seg (elems)
    int seg1 = ((4 + quad) ^ (l16 & 7)) * 8;  // kk=1 phys seg

    for (int k0 = 0; k0 < K; k0 += 64) {
#pragma unroll
        for (int c = 0; c < BM / 32; c++)
            gload_lds16(aBase + (size_t)c * rstride + k0, &As[c * 32 + r8][p8 * 8]);
#pragma unroll
        for (int c = 0; c < BN / 32; c++)
            gload_lds16(bBase + (size_t)c * rstride + k0, &Bs[c * 32 + r8][p8 * 8]);
        __syncthreads();
        v8s af[WI], bf[WJ];
        // kk = 0 (K cols k0..k0+31)
#pragma unroll
        for (int i = 0; i < WI; i++)
            af[i] = *(const v8s*)&As[wm * (WI * 16) + i * 16 + l16][seg0];
#pragma unroll
        for (int j = 0; j < WJ; j++)
            bf[j] = *(const v8s*)&Bs[wn * (WJ * 16) + j * 16 + l16][seg0];
#pragma unroll
        for (int i = 0; i < WI; i++)
#pragma unroll
            for (int j = 0; j < WJ; j++)
                acc[i][j] = __builtin_amdgcn_mfma_f32_16x16x32_bf16(af[i], bf[j],
                                                                    acc[i][j], 0, 0, 0);
        // kk = 1 (K cols k0+32..k0+63)
#pragma unroll
        for (int i = 0; i < WI; i++)
            af[i] = *(const v8s*)&As[wm * (WI * 16) + i * 16 + l16][seg1];
#pragma unroll
        for (int j = 0; j < WJ; j++)
            bf[j] = *(const v8s*)&Bs[wn * (WJ * 16) + j * 16 + l16][seg1];
#pragma unroll
        for (int i = 0; i < WI; i++)
#pragma unroll
            for (int j = 0; j < WJ; j++)
                acc[i][j] = __builtin_amdgcn_mfma_f32_16x16x32_bf16(af[i], bf[j],
                                                                    acc[i][j], 0, 0, 0);
        __syncthreads();
    }

#pragma unroll
    for (int i = 0; i < WI; i++) {
#pragma unroll
        for (int j = 0; j < WJ; j++) {
#pragma unroll
            for (int rr = 0; rr < 4; rr++) {
                int row = m0 + wm * (WI * 16) + i * 16 + quad * 4 + rr;
                int col = n0 + wn * (WJ * 16) + j * 16 + l16;
                float v = acc[i][j][rr];
                size_t oi = (size_t)row * N + col;
                if (EM == 0) {
                    ((u16*)out0)[oi] = f2bf(v);
                } else if (EM == 1) {
                    if (col < 1024) {
                        ((u16*)out0)[(size_t)row * 1024 + col] = f2bf(v);
                    } else {
                        // pre-activate: store silu(z) — scan PASS3 reads it 4x
                        float sz = v * sigmoidf_(v);
                        ((u16*)out1)[(size_t)row * 1024 + (col - 1024)] = f2bf(sz);
                    }
                } else if (EM == 5) {
                    ((float*)out0)[oi] = v;
                } else {
                    float g = aux1[row >> 10];
                    float res = ldf(aux0, oi, fin) + g * v;
                    if (fin) ((float*)out0)[oi] = res;
                    else ((u16*)out0)[oi] = f2bf(res);
                }
            }
        }
    }
}

// ---------------- tiled depthwise conv + SiLU (gather folded, LDS reuse) ----
// FUSED over directions: 4096 blocks; d = blockIdx.x >> 10.
__global__ __launch_bounds__(256) void conv_tile(const u16* __restrict__ xi,
                                                 const void* __restrict__ cw,
                                                 u16* __restrict__ xc4,
                                                 const int* __restrict__ flags,
                                                 const int* __restrict__ perm3) {
    int fin = flags[0];
    int gblk = blockIdx.x;
    int d = gblk >> 10, blk = gblk & 1023;
    int b = blk >> 7, tc = blk & 127;
    int t0 = tc * CTB;
    __shared__ u16 rows[CTB + 3][1024];
    __shared__ int sp[CTB + 3];
    if (threadIdx.x < CTB + 3) {
        int tt = t0 - 3 + (int)threadIdx.x;
        sp[threadIdx.x] = (tt >= 0) ? dirmap(d, tt, perm3) : -1;
    }
    __syncthreads();
    for (int i = threadIdx.x; i < (CTB + 3) * 128; i += 256) {
        int r = i >> 7, off = (i & 127) * 8;
        int src = sp[r];
        uint4 v = make_uint4(0, 0, 0, 0);
        if (src >= 0)
            v = *(const uint4*)(xi + ((size_t)(b * 1024 + src)) * 1024 + off);
        *(uint4*)&rows[r][off] = v;
    }
    int e0 = threadIdx.x * 4;
    float w[4][4];
#pragma unroll
    for (int ee = 0; ee < 4; ee++)
#pragma unroll
        for (int k = 0; k < 4; k++)
            w[ee][k] = ldf(cw, (size_t)(e0 + ee) * 4 + k, fin);
    __syncthreads();
    u16* outp = xc4 + (size_t)d * M1 * 1024;
#pragma unroll
    for (int t = 0; t < CTB; t++) {
        float a[4] = {0.f, 0.f, 0.f, 0.f};
#pragma unroll
        for (int k = 0; k < 4; k++) {
            uint2 v = *(const uint2*)&rows[t + k][e0];
            const u16* vs = (const u16*)&v;
#pragma unroll
            for (int ee = 0; ee < 4; ee++)
                a[ee] += w[ee][k] * bf2f(vs[ee]);
        }
        u16 o[4];
#pragma unroll
        for (int ee = 0; ee < 4; ee++) o[ee] = f2bf(a[ee] * sigmoidf_(a[ee]));
        *(uint2*)(outp + ((size_t)(b * 1024 + t0 + t)) * 1024 + e0) = *(const uint2*)o;
    }
}

// ---------------- chunked parallel scan (FUSED over dirs, e-PAIR/thread) ----
// R16: each thread owns TWO adjacent e-columns -> 2 independent dependency
// chains per thread (latency-bound loop, VALU 58%/HBM 20%) + u32 paired
// loads/stores for x/z/y (fixes scalar-u16 G13 violation, 128->256B/wave).
// grid: (ec 2) x (chunk 16) x (b 8) x (d 4) = 1024 blocks x 256 threads
// = 4 blocks/CU, one full generation. sdt/bc LDS reads shared by both cols.
// Fast path (A[e][s] == -(s+1), runtime-verified): E = 1/(1+exp(xp)) exactly;
// per-s decay = E^(s+1) chained. PASS1 stores Eprod; combine exponentiates.
// General path is cold: volatile A_log reloads (no LICM) keep it out of the
// fast path's register budget; __launch_bounds__(256,4) caps at 128 regs.
// NOTE (R12 lesson): do NOT hand-schedule within a chain — the serial-Ev
// form + compiler pipelining is optimal. This change adds a 2nd chain only.
#define SHUF_LO(q) __builtin_shufflevector(q, q, 0, 1)
#define SHUF_HI(q) __builtin_shufflevector(q, q, 2, 3)
#define SCAN_TLOOP(FASTV)                                                      \
    for (int t = 0; t < CLEN; t++) {                                           \
        u32 xnw = 0, znw = 0;                                                  \
        if (t + 1 < CLEN) {                                                    \
            xnw = *(const u32*)&xcyz[ix + 1024];                               \
            if (PASS == 3)                                                     \
                znw = *(const u32*)&zb[zbase + (size_t)s_perm[t + 1] * 1024];  \
        }                                                                      \
        v4f q0 = *(const v4f*)&sdt[t][0];                                      \
        v4f q1 = *(const v4f*)&sdt[t][4];                                      \
        v4f q2 = *(const v4f*)&sdt[t][8];                                      \
        v4f q3 = *(const v4f*)&sdt[t][12];                                     \
        v2f xpvA = {bdA, 0.f}, xpvB = {bdB, 0.f};                              \
        xpvA += SHUF_LO(q0) * wdtA[0]; xpvB += SHUF_LO(q0) * wdtB[0];          \
        xpvA += SHUF_HI(q0) * wdtA[1]; xpvB += SHUF_HI(q0) * wdtB[1];          \
        xpvA += SHUF_LO(q1) * wdtA[2]; xpvB += SHUF_LO(q1) * wdtB[2];          \
        xpvA += SHUF_HI(q1) * wdtA[3]; xpvB += SHUF_HI(q1) * wdtB[3];          \
        xpvA += SHUF_LO(q2) * wdtA[4]; xpvB += SHUF_LO(q2) * wdtB[4];          \
        xpvA += SHUF_HI(q2) * wdtA[5]; xpvB += SHUF_HI(q2) * wdtB[5];          \
        xpvA += SHUF_LO(q3) * wdtA[6]; xpvB += SHUF_LO(q3) * wdtB[6];          \
        xpvA += SHUF_HI(q3) * wdtA[7]; xpvB += SHUF_HI(q3) * wdtB[7];          \
        float xpA = xpvA.x + xpvA.y;                                           \
        float xpB = xpvB.x + xpvB.y;                                           \
        float exA = __expf(xpA);                                               \
        float exB = __expf(xpB);                                               \
        v4f r0 = *(const v4f*)&sdt[t][16];                                     \
        v4f r1 = *(const v4f*)&sdt[t][20];                                     \
        v4f r2 = *(const v4f*)&sdt[t][24];                                     \
        v4f r3 = *(const v4f*)&sdt[t][28];                                     \
        v2f bc[8];                                                             \
        bc[0] = SHUF_LO(r0); bc[1] = SHUF_HI(r0);                              \
        bc[2] = SHUF_LO(r1); bc[3] = SHUF_HI(r1);                              \
        bc[4] = SHUF_LO(r2); bc[5] = SHUF_HI(r2);                              \
        bc[6] = SHUF_LO(r3); bc[7] = SHUF_HI(r3);                              \
        v2f accA = {0.f, 0.f}, accB = {0.f, 0.f};                              \
        if (FASTV) {                                                           \
            float EA = rcp_(1.f + exA);                                        \
            float EB = rcp_(1.f + exB);                                        \
            v2f EvA; EvA.x = EA; EvA.y = EA * EA;                              \
            v2f EvB; EvB.x = EB; EvB.y = EB * EB;                              \
            v2f EsA; EsA.x = EvA.y; EsA.y = EvA.y;                             \
            v2f EsB; EsB.x = EvB.y; EsB.y = EvB.y;                             \
            _Pragma("unroll")                                                  \
            for (int p = 0; p < 8; p++) {                                      \
                hA[p] = hA[p] * EvA + bc[p] * xvA;                             \
                hB[p] = hB[p] * EvB + bc[p] * xvB;                             \
                accA += hA[p];                                                 \
                accB += hB[p];                                                 \
                EvA *= EsA;                                                    \
                EvB *= EsB;                                                    \
            }                                                                  \
            if (PASS == 1) { dsA *= EA; dsB *= EB; }                           \
        } else {                                                               \
            float dtvA = (xpA > 15.f) ? xpA : __logf(1.f + exA);               \
            float dtvB = (xpB > 15.f) ? xpB : __logf(1.f + exB);               \
            _Pragma("unroll")                                                  \
            for (int p = 0; p < 8; p++) {                                      \
                v2f esA, esB;                                                  \
                esA.x = __expf(-__expf(ldf_v(A_log, (size_t)e0 * 16 + 2 * p, fin)) * dtvA); \
                esA.y = __expf(-__expf(ldf_v(A_log, (size_t)e0 * 16 + 2 * p + 1, fin)) * dtvA); \
                esB.x = __expf(-__expf(ldf_v(A_log, (size_t)(e0 + 1) * 16 + 2 * p, fin)) * dtvB); \
                esB.y = __expf(-__expf(ldf_v(A_log, (size_t)(e0 + 1) * 16 + 2 * p + 1, fin)) * dtvB); \
                hA[p] = hA[p] * esA + bc[p] * xvA;                             \
                hB[p] = hB[p] * esB + bc[p] * xvB;                             \
                accA += hA[p];                                                 \
                accB += hB[p];                                                 \
            }                                                                  \
            if (PASS == 1) { dsA += dtvA; dsB += dtvB; }                       \
        }                                                                      \
        if (PASS == 3) {                                                       \
            float oA = (accA.x + accA.y) * zvA * wd;                           \
            float oB = (accB.x + accB.y) * zvB * wd;                           \
            u32 ow = (u32)f2bf(oA) | ((u32)f2bf(oB) << 16);                    \
            *(u32*)&xcyz[ix] = ow;                                             \
        }                                                                      \
        ix += 1024;                                                            \
        xvA = bf2f((u16)(xnw & 0xffff));                                       \
        xvB = bf2f((u16)(xnw >> 16));                                          \
        if (PASS == 3) {                                                       \
            zvA = bf2f((u16)(znw & 0xffff));                                   \
            zvB = bf2f((u16)(znw >> 16));                                      \
        }                                                                      \
    }

template <int PASS>
__global__ __launch_bounds__(256, 4) void scan_chunk(const float* __restrict__ dtbc,
                                                     u16* __restrict__ xcyz,
                                                     const u16* __restrict__ zb,
                                                     const void* __restrict__ A_log,
                                                     const void* __restrict__ W_dt,
                                                     const void* __restrict__ b_dt,
                                                     const int* __restrict__ flags,
                                                     float* __restrict__ hend,
                                                     float* __restrict__ dtsum,
                                                     const void* __restrict__ dirw,
                                                     const int* __restrict__ perm3) {
    int fin = flags[0];
    int bid = blockIdx.x;
    int ec = bid & 1, c = (bid >> 1) & (NCHUNK - 1), b = (bid >> 5) & 7, d = bid >> 8;
    int e0 = ec * 512 + (int)threadIdx.x * 2;              // this thread's e-pair
    size_t row0 = (size_t)d * M1 + b * 1024 + c * CLEN;    // global A row
    size_t cix  = (size_t)d * (8 * NCHUNK) + b * NCHUNK + c;  // chunk index
    __shared__ float sdt[CLEN][32];
    __shared__ int s_perm[CLEN];
    {
        const float* src = dtbc + row0 * 64;
        for (int i = threadIdx.x; i < CLEN * 8; i += 256) {
            int t = i >> 3, f = i & 7;                     // CLEN rows x 8 f4
            *(float4*)&sdt[t][f * 4] = *(const float4*)(src + (size_t)t * 64 + f * 4);
        }
        if (PASS == 3 && threadIdx.x < CLEN)
            s_perm[threadIdx.x] = dirmap(d, c * CLEN + (int)threadIdx.x, perm3);
    }
    bool fast = true;
#pragma unroll
    for (int p = 0; p < 8; p++) {
        float a0 = -__expf(ldf(A_log, (size_t)e0 * 16 + 2 * p, fin));
        float a1 = -__expf(ldf(A_log, (size_t)e0 * 16 + 2 * p + 1, fin));
        float b0 = -__expf(ldf(A_log, (size_t)(e0 + 1) * 16 + 2 * p, fin));
        float b1 = -__expf(ldf(A_log, (size_t)(e0 + 1) * 16 + 2 * p + 1, fin));
        fast = fast && fabsf(a0 + (float)(2 * p + 1)) < 1e-3f * (2 * p + 1)
                    && fabsf(a1 + (float)(2 * p + 2)) < 1e-3f * (2 * p + 2)
                    && fabsf(b0 + (float)(2 * p + 1)) < 1e-3f * (2 * p + 1)
                    && fabsf(b1 + (float)(2 * p + 2)) < 1e-3f * (2 * p + 2);
    }
    v2f wdtA[8], wdtB[8];
#pragma unroll
    for (int p = 0; p < 8; p++) {
        wdtA[p].x = ldf(W_dt, (size_t)(2 * p) * 1024 + e0, fin);
        wdtA[p].y = ldf(W_dt, (size_t)(2 * p + 1) * 1024 + e0, fin);
        wdtB[p].x = ldf(W_dt, (size_t)(2 * p) * 1024 + e0 + 1, fin);
        wdtB[p].y = ldf(W_dt, (size_t)(2 * p + 1) * 1024 + e0 + 1, fin);
    }
    float bdA = ldf(b_dt, e0, fin);
    float bdB = ldf(b_dt, e0 + 1, fin);
    float wd = (PASS == 3) ? ldf(dirw, d, fin) : 0.f;
    v2f hA[8], hB[8];
    if (PASS == 1) {
#pragma unroll
        for (int p = 0; p < 8; p++) {
            hA[p] = (v2f){0.f, 0.f};
            hB[p] = (v2f){0.f, 0.f};
        }
    } else {
#pragma unroll
        for (int p = 0; p < 8; p++) {
            v2f lo_ = *(const v2f*)&hend[(cix * 16 + 2 * p) * 1024 + e0];
            v2f hi_ = *(const v2f*)&hend[(cix * 16 + 2 * p + 1) * 1024 + e0];
            hA[p] = (v2f){lo_.x, hi_.x};
            hB[p] = (v2f){lo_.y, hi_.y};
        }
    }
    __syncthreads();
    float dsA = fast ? 1.f : 0.f;      // Eprod (fast) or dt-sum (general)
    float dsB = dsA;
    size_t ix = row0 * 1024 + e0;
    size_t zbase = (size_t)b * 1024 * 1024 + e0;
    u32 xw0 = *(const u32*)&xcyz[ix];              // prefetch t=0 (pair)
    float xvA = bf2f((u16)(xw0 & 0xffff));
    float xvB = bf2f((u16)(xw0 >> 16));
    float zvA = 0.f, zvB = 0.f;
    if (PASS == 3) {
        u32 zw0 = *(const u32*)&zb[zbase + (size_t)s_perm[0] * 1024];
        zvA = bf2f((u16)(zw0 & 0xffff));
        zvB = bf2f((u16)(zw0 >> 16));
    }
    if (fast) {
        SCAN_TLOOP(true)
    } else {
        SCAN_TLOOP(false)
    }
    if (PASS == 1) {
#pragma unroll
        for (int p = 0; p < 8; p++) {
            *(v2f*)&hend[(cix * 16 + 2 * p) * 1024 + e0] = (v2f){hA[p].x, hB[p].x};
            *(v2f*)&hend[(cix * 16 + 2 * p + 1) * 1024 + e0] = (v2f){hA[p].y, hB[p].y};
        }
        *(v2f*)&dtsum[cix * 1024 + e0] = (v2f){dsA, dsB};
    }
}

// combine parallelized over (d, b, s, ec): 2048 blocks, each thread owns one
// (d,b,e,s) chain; sequential over c (NCHUNK=16 steps). Fast mode (same
// runtime A-check as scan_chunk): dtsum holds Eprod; decay = Eprod^(s+1) by
// binary exponentiation (no exp). General: exp(Ae*ds).
__global__ __launch_bounds__(256) void scan_combine2(float* __restrict__ hend,
                                                     const float* __restrict__ dtsum,
                                                     const void* __restrict__ A_log,
                                                     const int* __restrict__ flags) {
    int fin = flags[0];
    int bid = blockIdx.x;            // d*512 + b*64 + s*4 + ec
    int ec = bid & 3, s = (bid >> 2) & 15, b = (bid >> 6) & 7, d = bid >> 9;
    int e = ec * 256 + threadIdx.x;
    bool fast = true;
#pragma unroll
    for (int s2 = 0; s2 < 16; s2++) {
        float a = -__expf(ldf(A_log, (size_t)e * 16 + s2, fin));
        fast = fast && fabsf(a + (float)(s2 + 1)) < 1e-3f * (s2 + 1);
    }
    float Ae = -__expf(ldf(A_log, (size_t)e * 16 + s, fin));
    float H = 0.f;
    size_t base = (size_t)d * (8 * NCHUNK) + (size_t)b * NCHUNK;
    for (int c = 0; c < NCHUNK; c++) {
        size_t cix = base + c;
        float ds = dtsum[cix * 1024 + e];
        float decay;
        if (fast) {
            float r = 1.f, bb = ds;
            int n = s + 1;
            while (n) {
                if (n & 1) r *= bb;
                bb *= bb;
                n >>= 1;
            }
            decay = r;
        } else {
            decay = __expf(Ae * ds);
        }
        size_t idx = (cix * 16 + s) * 1024 + e;
        float loc = hend[idx];
        hend[idx] = H;
        H = loc + decay * H;
    }
}

// ---------------- LayerNorm with fused 4-direction gather-sum ---------------
// y4: 4 planes [d][b*1024+t][1024] bf16, direction order, dir_w pre-folded.
// Natural row (b,q) gathers t0=q, t1=1023-q, t2=transpose(q), t3=inv3[q].
__global__ __launch_bounds__(256) void ln4_kernel(const u16* __restrict__ y4,
                                                  const void* __restrict__ ln_g,
                                                  const void* __restrict__ ln_b,
                                                  const int* __restrict__ flags,
                                                  const int* __restrict__ inv3,
                                                  u16* __restrict__ fn) {
    int fin = flags[0];
    int row = blockIdx.x;            // b*1024 + q
    int b = row >> 10, q = row & 1023;
    int t1 = 1023 - q;
    int t2 = ((q & 31) << 5) | (q >> 5);
    int t3 = inv3[q];
    const u16* p0 = y4 + ((size_t)(b * 1024 + q)) * 1024;
    const u16* p1 = y4 + ((size_t)(M1 + b * 1024 + t1)) * 1024;
    const u16* p2 = y4 + ((size_t)(2 * M1 + b * 1024 + t2)) * 1024;
    const u16* p3 = y4 + ((size_t)(3 * M1 + b * 1024 + t3)) * 1024;
    int e0 = threadIdx.x * 4;
    uint2 a0 = *(const uint2*)(p0 + e0);
    uint2 a1 = *(const uint2*)(p1 + e0);
    uint2 a2 = *(const uint2*)(p2 + e0);
    uint2 a3 = *(const uint2*)(p3 + e0);
    const u16* s0 = (const u16*)&a0;
    const u16* s1 = (const u16*)&a1;
    const u16* s2 = (const u16*)&a2;
    const u16* s3 = (const u16*)&a3;
    float v[4];
    float sum = 0.f, sq = 0.f;
#pragma unroll
    for (int j = 0; j < 4; j++) {
        float f = bf2f(s0[j]) + bf2f(s1[j]) + bf2f(s2[j]) + bf2f(s3[j]);
        v[j] = f;
        sum += f;
        sq += f * f;
    }
    __shared__ float r1[256], r2[256];
    r1[threadIdx.x] = sum;
    r2[threadIdx.x] = sq;
    __syncthreads();
    for (int s = 128; s > 0; s >>= 1) {
        if (threadIdx.x < s) {
            r1[threadIdx.x] += r1[threadIdx.x + s];
            r2[threadIdx.x] += r2[threadIdx.x + s];
        }
        __syncthreads();
    }
    float mu = r1[0] * (1.f / 1024.f);
    float var = r2[0] * (1.f / 1024.f) - mu * mu;
    float rs = rsqrtf(var + 1e-5f);
    u16 o[4];
#pragma unroll
    for (int j = 0; j < 4; j++) {
        int e = e0 + j;
        o[j] = f2bf((v[j] - mu) * rs * ldf(ln_g, e, fin) + ldf(ln_b, e, fin));
    }
    *(uint2*)(fn + (size_t)row * 1024 + e0) = *(const uint2*)o;
}

// ---------------- gate: partial col sums -> shared matvec -> finisher -------
__global__ __launch_bounds__(256) void gate_partial(const u16* __restrict__ vfb,
                                                    float* __restrict__ meanv) {
    int b = blockIdx.x >> 4, tc = blockIdx.x & 15;
    float s[4] = {0.f, 0.f, 0.f, 0.f};
    const u16* base = vfb + ((size_t)b * 1024 + tc * 64) * 1024;
    for (int t = 0; t < 64; t++) {
#pragma unroll
        for (int k = 0; k < 4; k++)
            s[k] += bf2f(base[(size_t)t * 1024 + threadIdx.x + k * 256]);
    }
#pragma unroll
    for (int k = 0; k < 4; k++)
        atomicAdd(&meanv[b * 1024 + threadIdx.x + k * 256], s[k]);
}

__global__ __launch_bounds__(256) void gate_mv(const float* __restrict__ meanv,
                                               const void* __restrict__ Wg1,
                                               const int* __restrict__ flags,
                                               float* __restrict__ gpart) {
    int fin = flags[0];
    int kc = blockIdx.x, j = threadIdx.x;
    __shared__ float mv[8][32];
    if (threadIdx.x < 8 * 32) {
        int b = threadIdx.x >> 5, kk = threadIdx.x & 31;
        mv[b][kk] = meanv[b * 1024 + kc * 32 + kk] * (1.f / 1024.f);
    }
    __syncthreads();
    float acc[8];
#pragma unroll
    for (int b = 0; b < 8; b++) acc[b] = 0.f;
    for (int kk = 0; kk < 32; kk++) {
        float w = ldf(Wg1, (size_t)(kc * 32 + kk) * 256 + j, fin);
#pragma unroll
        for (int b = 0; b < 8; b++) acc[b] += mv[b][kk] * w;
    }
#pragma unroll
    for (int b = 0; b < 8; b++) atomicAdd(&gpart[b * 256 + j], acc[b]);
}

__global__ __launch_bounds__(256) void gate_fin2(const float* __restrict__ gpart,
                                                 const void* __restrict__ Wg2,
                                                 const int* __restrict__ flags,
                                                 float* __restrict__ g) {
    int fin = flags[0];
    int b = blockIdx.x, j = threadIdx.x;
    __shared__ float red[256];
    float a = gpart[b * 256 + j];
    float si = a * sigmoidf_(a);
    red[j] = si * ldf(Wg2, j, fin);
    __syncthreads();
    for (int st = 128; st > 0; st >>= 1) {
        if (j < st) red[j] += red[j + st];
        __syncthreads();
    }
    if (j == 0) g[b] = sigmoidf_(red[0]);
}

// ---------------- launch ----------------------------------------------------
extern "C" void kernel_launch(void* const* d_in, const int* in_sizes, int n_in,
                              void* d_out, int out_size, void* d_ws, size_t ws_size,
                              hipStream_t stream) {
    const void* vf_raw  = d_in[0];
    const void* W_input = d_in[1];
    const void* W_in    = d_in[2];
    const void* conv_w  = d_in[3];
    const void* W_xproj = d_in[4];
    const void* W_dt    = d_in[5];
    const void* b_dt    = d_in[6];
    const void* A_log   = d_in[7];
    const void* W_outm  = d_in[8];
    const void* dir_w   = d_in[9];
    const void* ln_g    = d_in[10];
    const void* ln_b    = d_in[11];
    const void* W_outpj = d_in[12];
    const void* Wg1     = d_in[13];
    const void* Wg2     = d_in[14];

    char* ws = (char*)d_ws;
    size_t off = 0;
    auto alloc = [&](size_t bytes) -> void* {
        void* p = ws + off;
        off = (off + bytes + 255) & ~(size_t)255;
        return p;
    };
    int*   flags = (int*)alloc(256);
    int*   perm3 = (int*)alloc(NN * 4);
    int*   inv3  = (int*)alloc(NN * 4);
    float* meanv = (float*)alloc(8 * 1024 * 4);
    float* gpart = (float*)alloc(8 * 256 * 4);   // contiguous after meanv
    float* gbuf  = (float*)alloc(64);
    u16*   WiB   = (u16*)alloc((size_t)1024 * 1024 * 2);   // W_input bf16 (Bt fmt)
    u16*   WtIn  = (u16*)alloc((size_t)2048 * 1024 * 2);
    u16*   WtF   = (u16*)alloc((size_t)2048 * 1024 * 2);   // fused (W_in^T@W_input^T)
    u16*   WtXp  = (u16*)alloc((size_t)64 * 1024 * 2);
    u16*   WtOm  = (u16*)alloc((size_t)1024 * 1024 * 2);
    u16*   WtOp  = (u16*)alloc((size_t)1024 * 1024 * 2);
    // --- 64 MiB region reused over the pipeline lifetime:
    //     (1) vfb(16M)+xbuf(16M) early (convert/gate/EM1);
    //     (2) hend4 = 32 MiB during the scans;
    //     (3) y4 = 4 bf16 direction-planes (64 MiB) for EM3-seq -> ln4.
    u16*   vfb   = (u16*)alloc((size_t)M1 * 1024 * 2);
    u16*   xbuf  = (u16*)alloc((size_t)M1 * 1024 * 2);    // (dead; alias filler)
    float* tail32= (float*)alloc((size_t)M1 * 1024 * 4);  // completes the 64 MiB
    u16*   xi    = (u16*)alloc((size_t)M1 * 1024 * 2);   // later: fn
    u16*   zb    = (u16*)alloc((size_t)M1 * 1024 * 2);
    u16*   xc4   = (u16*)alloc((size_t)M4 * 1024 * 2);   // 4 dir-planes, 64 MiB
    float* dtbc4 = (float*)alloc((size_t)M4 * 64 * 4);   // 8 MiB
    float* dtsum4= (float*)alloc((size_t)4 * 8 * NCHUNK * 1024 * 4);  // 2 MiB
    float* hend4 = (float*)vfb;
    u16*   y4    = (u16*)vfb;
    (void)tail32;
    (void)xbuf;

    setup_kernel<<<4, 256, 0, stream>>>((const u16*)vf_raw, flags, perm3, inv3);
    convert_bf<<<(M1 * 1024) / 256, 256, 0, stream>>>(vf_raw, vfb, flags, M1 * 1024);
    // W_input: plain bf16 convert (native row-major IS the Bt layout needed below)
    convert_bf<<<(1024 * 1024) / 256, 256, 0, stream>>>(W_input, WiB, flags, 1024 * 1024);
    // all four weight transposes in one dispatch
    transpose_pad4<<<dim3(32, 130), 256, 0, stream>>>(
        W_in, WtIn, W_xproj, WtXp, W_outm, WtOm, W_outpj, WtOp, flags);
    // meanv + gpart are contiguous: one zero-fill
    zero_f32<<<40, 256, 0, stream>>>(meanv, 8 * 1024 + 8 * 256);

    // Fused weight: WtF[m][k] = sum_j W_in[j][m] * W_input[k][j]
    //             = (W_input @ W_in)^T  — exactly the Bt layout for stage 2.
    // Small (6 MB, L2-resident) -> 64x64 tiles for grid occupancy (512 blocks).
    gemm128<0, 2, 2><<<dim3(32, 16), 256, 0, stream>>>(
        WtIn, WiB, WtF, nullptr, 2048, 1024, 1024, flags, nullptr, nullptr);

    // gate (uses vfb before hend4 aliases it — stream-ordered)
    gate_partial<<<128, 256, 0, stream>>>(vfb, meanv);
    gate_mv<<<32, 256, 0, stream>>>(meanv, Wg1, flags, gpart);
    gate_fin2<<<8, 256, 0, stream>>>(gpart, Wg2, flags, gbuf);

    // stage 1+2 fused: xz = vf @ (W_input @ W_in) -> xi, silu(z)
    gemm128<1, 4, 4><<<dim3(64, 16), 256, 0, stream>>>(
        vfb, WtF, xi, zb, M1, 2048, 1024, flags, nullptr, nullptr);

    // ---- all four directions batched (independent given xi, zb) ----
    conv_tile<<<4096, 256, 0, stream>>>(xi, conv_w, xc4, flags, perm3);
    // dtbc via the BK=64 GEMM template (EM=5 fp32 store): 64x64 tiles, (512,1)
    gemm128<5, 2, 2><<<dim3(512, 1), 256, 0, stream>>>(
        xc4, WtXp, dtbc4, nullptr, M4, 64, 1024, flags, nullptr, nullptr);
    scan_chunk<1><<<1024, 256, 0, stream>>>(dtbc4, xc4, zb, A_log, W_dt, b_dt,
                                            flags, hend4, dtsum4, dir_w, perm3);
    scan_combine2<<<2048, 256, 0, stream>>>(hend4, dtsum4, A_log, flags);
    scan_chunk<3><<<1024, 256, 0, stream>>>(dtbc4, xc4, zb, A_log, W_dt, b_dt,
                                            flags, hend4, dtsum4, dir_w, perm3);

    // hend4 dead -> y4 reuses the same 64 MiB. One fused plain-store GEMM:
    // y4[d] = (w_d * y_d) @ W_outm, 128x128 tiles (2048 blocks).
    gemm128<0, 4, 4><<<dim3(256, 8), 256, 0, stream>>>(
        xc4, WtOm, y4, nullptr, M4, 1024, 1024, flags, nullptr, nullptr);

    // LayerNorm fused with the 4-direction gather-sum (row-granular gathers).
    u16* fn = xi;  // xi dead after conv
    ln4_kernel<<<M1, 256, 0, stream>>>(y4, ln_g, ln_b, flags, inv3, fn);
    gemm128<4, 4, 4><<<dim3(64, 8), 256, 0, stream>>>(
        fn, WtOp, d_out, nullptr, M1, 1024, 1024, flags, vf_raw, gbuf);
}

// Round 17
// 612.957 us; speedup vs baseline: 1.0201x; 1.0201x over previous
//
#include <hip/hip_runtime.h>

typedef unsigned short u16;
typedef unsigned int u32;
typedef short v8s __attribute__((ext_vector_type(8)));
typedef float v4f __attribute__((ext_vector_type(4)));
typedef float v2f __attribute__((ext_vector_type(2)));

#define B_SZ 8
#define HH 32
#define WW 32
#define NN 1024          // H*W
#define M1 (B_SZ * NN)   // 8192 rows (one direction)
#define M4 (4 * M1)      // 32768 rows (all four directions)
#define NCHUNK 16
#define CLEN 64          // NCHUNK*CLEN = 1024
#define CTB 8            // conv t-rows per block

__device__ __forceinline__ float bf2f(u16 u) {
    u32 x = ((u32)u) << 16;
    return __builtin_bit_cast(float, x);
}
__device__ __forceinline__ u16 f2bf(float f) {
    u32 x = __builtin_bit_cast(u32, f);
    x = x + 0x7fffu + ((x >> 16) & 1u);
    return (u16)(x >> 16);
}
// single v_rcp_f32 (~1 ulp) instead of the precise-div sequence
__device__ __forceinline__ float rcp_(float x) { return __builtin_amdgcn_rcpf(x); }
__device__ __forceinline__ float sigmoidf_(float x) { return rcp_(1.f + __expf(-x)); }
__device__ __forceinline__ float ldf(const void* p, size_t i, int fin) {
    return fin ? ((const float*)p)[i] : bf2f(((const u16*)p)[i]);
}
__device__ __forceinline__ u16 ldbf(const void* p, size_t i, int fin) {
    return fin ? f2bf(((const float*)p)[i]) : ((const u16*)p)[i];
}
// async global->LDS, 16B per lane; LDS dest = wave-uniform base + lane*16
__device__ __forceinline__ void gload_lds16(const u16* g, u16* l) {
    __builtin_amdgcn_global_load_lds(
        (const __attribute__((address_space(1))) unsigned int*)g,
        (__attribute__((address_space(3))) unsigned int*)l, 16, 0, 0);
}
__device__ __forceinline__ int dirmap(int d, int t, const int* __restrict__ perm3) {
    if (d == 0) return t;
    if (d == 1) return (NN - 1) - t;
    if (d == 2) return (t & (HH - 1)) * WW + (t >> 5);
    return perm3[t];
}

// ---------------- setup: dtype sniffer + diagonal permutation (merged) ------
__global__ void setup_kernel(const u16* __restrict__ raw, int* __restrict__ flags,
                             int* __restrict__ perm, int* __restrict__ inv) {
    if (blockIdx.x == 0 && threadIdx.x == 0) {
        int ok = 0;
        for (int i = 0; i < 512; i++) {
            int e = (raw[i] >> 7) & 0xFF;
            ok += (e >= 100 && e <= 140) ? 1 : 0;
        }
        flags[0] = (ok < 460) ? 1 : 0;
    }
    int t = blockIdx.x * blockDim.x + threadIdx.x;
    if (t >= NN) return;
    int i = t / WW, j = t % WW;
    int off = j - i;
    int start = 0;
    for (int o = -(HH - 1); o < off; ++o) {
        int lo = (0 > -o) ? 0 : -o;
        int hi = (HH - 1 < WW - 1 - o) ? (HH - 1) : (WW - 1 - o);
        start += (hi - lo + 1);
    }
    int lo0 = (0 > -off) ? 0 : -off;
    int r = start + (i - lo0);
    perm[r] = t;
    inv[t] = r;
}

__global__ __launch_bounds__(256) void convert_bf(const void* __restrict__ src,
                                                  u16* __restrict__ dst,
                                                  const int* __restrict__ flags, int n) {
    int fin = flags[0];
    int i = blockIdx.x * 256 + threadIdx.x;
    if (i < n) dst[i] = ldbf(src, (size_t)i, fin);
}

__global__ __launch_bounds__(256) void zero_f32(float* __restrict__ p, int n) {
    int i = blockIdx.x * 256 + threadIdx.x;
    if (i < n) p[i] = 0.f;
}

// ---------------- batched weight transpose+pad: 4 weights, one dispatch -----
// grid (32, 130): y in [0,64) W_in(Nsrc=2048); [64,66) W_xproj(32);
// [66,98) W_outm(1024); [98,130) W_outpj(1024). All K=1024.
__global__ __launch_bounds__(256) void transpose_pad4(
        const void* __restrict__ s0, u16* __restrict__ d0,      // W_in
        const void* __restrict__ s1, u16* __restrict__ d1,      // W_xproj
        const void* __restrict__ s2, u16* __restrict__ d2,      // W_outm
        const void* __restrict__ s3, u16* __restrict__ d3,      // W_outpj
        const int* __restrict__ flags) {
    int fin = flags[0];
    const int K = 1024;
    int yb = blockIdx.y;
    const void* src;
    u16* dst;
    int Nsrc, n0;
    if (yb < 64)       { src = s0; dst = d0; Nsrc = 2048; n0 = yb * 32; }
    else if (yb < 66)  { src = s1; dst = d1; Nsrc = 32;   n0 = (yb - 64) * 32; }
    else if (yb < 98)  { src = s2; dst = d2; Nsrc = 1024; n0 = (yb - 66) * 32; }
    else               { src = s3; dst = d3; Nsrc = 1024; n0 = (yb - 98) * 32; }
    __shared__ u16 tile[32][33];
    int k0 = blockIdx.x * 32;
    int tx = threadIdx.x & 31, ty = threadIdx.x >> 5;
#pragma unroll
    for (int i = 0; i < 4; i++) {
        int k = k0 + ty + i * 8, n = n0 + tx;
        tile[ty + i * 8][tx] = (n < Nsrc) ? ldbf(src, (size_t)k * Nsrc + n, fin) : (u16)0;
    }
    __syncthreads();
#pragma unroll
    for (int i = 0; i < 4; i++) {
        int n = n0 + ty + i * 8, k = k0 + tx;
        dst[(size_t)n * K + k] = tile[tx][ty + i * 8];
    }
}

// ---------------- BMxBN MFMA GEMM, BK=64 (global_load_lds + XOR swizzle) ----
// C(MxN) = A(MxK) * Bt(NxK)^T. 256 thr = 4 waves (2x2); wave (WI*16)x(WJ*16).
// R14: K-step 64 — halves the vmcnt(0)+barrier drains per K-loop (verified:
// 640->614, bit-identical). 8-seg XOR swizzle for 128-B rows: phys seg p8 of
// row r holds logical p8^(r&7); reads phys=(kk*4+quad)^(l16&7).
// __launch_bounds__(256,4): cap unified regs at 128 — verified R9 (+1 wave).
// EM: 0 bf16 plain store; 1 split xz -> xi, silu(z) pre-activated (N=2048);
//     4 final out = vf + g*acc (aux0=vf raw, aux1=g); 5 fp32 plain store
//     (dtbc: WI=WJ=2, grid (512,1)).
template <int EM, int WI, int WJ>
__global__ __launch_bounds__(256, 4) void gemm128(const u16* __restrict__ A,
                                                  const u16* __restrict__ Bt,
                                                  void* __restrict__ out0,
                                                  void* __restrict__ out1,
                                                  int M, int N, int K,
                                                  const int* __restrict__ flags,
                                                  const void* __restrict__ aux0,
                                                  const float* __restrict__ aux1) {
    constexpr int BM = WI * 32;
    constexpr int BN = WJ * 32;
    int fin = flags[0];
    __shared__ __align__(16) u16 As[BM][64];
    __shared__ __align__(16) u16 Bs[BN][64];
    int tid = threadIdx.x;
    int wave = tid >> 6, lane = tid & 63, quad = lane >> 4, l16 = lane & 15;
    int wm = wave >> 1, wn = wave & 1;
    int m0 = blockIdx.x * BM, n0 = blockIdx.y * BN;
    int r8 = tid >> 3, p8 = tid & 7;          // 32 rows x 8 segs per gload call
    int sw = (p8 ^ (r8 & 7)) * 8;             // inverse-swizzled src seg (elems)

    const u16* aBase = A  + (size_t)(m0 + r8) * K + sw;
    const u16* bBase = Bt + (size_t)(n0 + r8) * K + sw;
    size_t rstride = (size_t)32 * K;          // 32 rows per gload call

    v4f acc[WI][WJ];
#pragma unroll
    for (int i = 0; i < WI; i++)
#pragma unroll
        for (int j = 0; j < WJ; j++) acc[i][j] = (v4f){0.f, 0.f, 0.f, 0.f};

    int seg0 = ((0 + quad) ^ (l16 & 7)) * 8;  // kk=0 phys seg (elems)
    int seg1 = ((4 + quad) ^ (l16 & 7)) * 8;  // kk=1 phys seg

    for (int k0 = 0; k0 < K; k0 += 64) {
#pragma unroll
        for (int c = 0; c < BM / 32; c++)
            gload_lds16(aBase + (size_t)c * rstride + k0, &As[c * 32 + r8][p8 * 8]);
#pragma unroll
        for (int c = 0; c < BN / 32; c++)
            gload_lds16(bBase + (size_t)c * rstride + k0, &Bs[c * 32 + r8][p8 * 8]);
        __syncthreads();
        v8s af[WI], bf[WJ];
        // kk = 0 (K cols k0..k0+31)
#pragma unroll
        for (int i = 0; i < WI; i++)
            af[i] = *(const v8s*)&As[wm * (WI * 16) + i * 16 + l16][seg0];
#pragma unroll
        for (int j = 0; j < WJ; j++)
            bf[j] = *(const v8s*)&Bs[wn * (WJ * 16) + j * 16 + l16][seg0];
#pragma unroll
        for (int i = 0; i < WI; i++)
#pragma unroll
            for (int j = 0; j < WJ; j++)
                acc[i][j] = __builtin_amdgcn_mfma_f32_16x16x32_bf16(af[i], bf[j],
                                                                    acc[i][j], 0, 0, 0);
        // kk = 1 (K cols k0+32..k0+63)
#pragma unroll
        for (int i = 0; i < WI; i++)
            af[i] = *(const v8s*)&As[wm * (WI * 16) + i * 16 + l16][seg1];
#pragma unroll
        for (int j = 0; j < WJ; j++)
            bf[j] = *(const v8s*)&Bs[wn * (WJ * 16) + j * 16 + l16][seg1];
#pragma unroll
        for (int i = 0; i < WI; i++)
#pragma unroll
            for (int j = 0; j < WJ; j++)
                acc[i][j] = __builtin_amdgcn_mfma_f32_16x16x32_bf16(af[i], bf[j],
                                                                    acc[i][j], 0, 0, 0);
        __syncthreads();
    }

#pragma unroll
    for (int i = 0; i < WI; i++) {
#pragma unroll
        for (int j = 0; j < WJ; j++) {
#pragma unroll
            for (int rr = 0; rr < 4; rr++) {
                int row = m0 + wm * (WI * 16) + i * 16 + quad * 4 + rr;
                int col = n0 + wn * (WJ * 16) + j * 16 + l16;
                float v = acc[i][j][rr];
                size_t oi = (size_t)row * N + col;
                if (EM == 0) {
                    ((u16*)out0)[oi] = f2bf(v);
                } else if (EM == 1) {
                    if (col < 1024) {
                        ((u16*)out0)[(size_t)row * 1024 + col] = f2bf(v);
                    } else {
                        // pre-activate: store silu(z) — scan PASS3 reads it 4x
                        float sz = v * sigmoidf_(v);
                        ((u16*)out1)[(size_t)row * 1024 + (col - 1024)] = f2bf(sz);
                    }
                } else if (EM == 5) {
                    ((float*)out0)[oi] = v;
                } else {
                    float g = aux1[row >> 10];
                    float res = ldf(aux0, oi, fin) + g * v;
                    if (fin) ((float*)out0)[oi] = res;
                    else ((u16*)out0)[oi] = f2bf(res);
                }
            }
        }
    }
}

// ---------------- tiled depthwise conv + SiLU (gather folded, LDS reuse) ----
// FUSED over directions: 4096 blocks; d = blockIdx.x >> 10.
__global__ __launch_bounds__(256) void conv_tile(const u16* __restrict__ xi,
                                                 const void* __restrict__ cw,
                                                 u16* __restrict__ xc4,
                                                 const int* __restrict__ flags,
                                                 const int* __restrict__ perm3) {
    int fin = flags[0];
    int gblk = blockIdx.x;
    int d = gblk >> 10, blk = gblk & 1023;
    int b = blk >> 7, tc = blk & 127;
    int t0 = tc * CTB;
    __shared__ u16 rows[CTB + 3][1024];
    __shared__ int sp[CTB + 3];
    if (threadIdx.x < CTB + 3) {
        int tt = t0 - 3 + (int)threadIdx.x;
        sp[threadIdx.x] = (tt >= 0) ? dirmap(d, tt, perm3) : -1;
    }
    __syncthreads();
    for (int i = threadIdx.x; i < (CTB + 3) * 128; i += 256) {
        int r = i >> 7, off = (i & 127) * 8;
        int src = sp[r];
        uint4 v = make_uint4(0, 0, 0, 0);
        if (src >= 0)
            v = *(const uint4*)(xi + ((size_t)(b * 1024 + src)) * 1024 + off);
        *(uint4*)&rows[r][off] = v;
    }
    int e0 = threadIdx.x * 4;
    float w[4][4];
#pragma unroll
    for (int ee = 0; ee < 4; ee++)
#pragma unroll
        for (int k = 0; k < 4; k++)
            w[ee][k] = ldf(cw, (size_t)(e0 + ee) * 4 + k, fin);
    __syncthreads();
    u16* outp = xc4 + (size_t)d * M1 * 1024;
#pragma unroll
    for (int t = 0; t < CTB; t++) {
        float a[4] = {0.f, 0.f, 0.f, 0.f};
#pragma unroll
        for (int k = 0; k < 4; k++) {
            uint2 v = *(const uint2*)&rows[t + k][e0];
            const u16* vs = (const u16*)&v;
#pragma unroll
            for (int ee = 0; ee < 4; ee++)
                a[ee] += w[ee][k] * bf2f(vs[ee]);
        }
        u16 o[4];
#pragma unroll
        for (int ee = 0; ee < 4; ee++) o[ee] = f2bf(a[ee] * sigmoidf_(a[ee]));
        *(uint2*)(outp + ((size_t)(b * 1024 + t0 + t)) * 1024 + e0) = *(const uint2*)o;
    }
}

// ---------------- chunked parallel scan (FUSED over directions) -------------
// grid: (ec 4) x (chunk 16) x (b 8) x (d 4) = 2048 blocks x 256 threads.
// PASS3 reads PRE-ACTIVATED silu(z) gathered through P_d (written by EM1)
// and folds dir_w[d] into the output.
// Fast path (A[e][s] == -(s+1), runtime-verified): decay base
//   E = exp(-softplus(xp)) = 1/(1+exp(xp))  [exact identity]
// -> ONE exp + one v_rcp per t; per-s decay = E^(s+1) by chained pk-muls.
// PASS1 stores the running PRODUCT of E; combine raises it to (s+1) by
// binary exponentiation. General path (non-arange A) unchanged.
// NOTE — this serial-Ev, one-e-per-thread formulation IS the optimum.
// Measured alternatives, all worse: R10 CLEN=64@2048->1 gen reshape (+5),
// R12 tree-ILP (+8), R16 e-pair 2-chain (+18, occupancy 53->34%). The loop
// is latency-bound and TLP at 8 waves/SIMD does the hiding — do not trade
// waves for per-thread ILP, and do not hand-schedule the chain.
#define SHUF_LO(q) __builtin_shufflevector(q, q, 0, 1)
#define SHUF_HI(q) __builtin_shufflevector(q, q, 2, 3)
#define SCAN_TLOOP(FASTV)                                                      \
    for (int t = 0; t < CLEN; t++) {                                           \
        float xn = 0.f, zn = 0.f;                                              \
        if (t + 1 < CLEN) {                                                    \
            xn = bf2f(xcyz[ix + 1024]);                                        \
            if (PASS == 3) zn = bf2f(zb[zbase + (size_t)s_perm[t + 1] * 1024]);\
        }                                                                      \
        v4f q0 = *(const v4f*)&sdt[t][0];                                      \
        v4f q1 = *(const v4f*)&sdt[t][4];                                      \
        v4f q2 = *(const v4f*)&sdt[t][8];                                      \
        v4f q3 = *(const v4f*)&sdt[t][12];                                     \
        v2f xpv = {bd, 0.f};                                                   \
        xpv += SHUF_LO(q0) * wdt2[0];                                          \
        xpv += SHUF_HI(q0) * wdt2[1];                                          \
        xpv += SHUF_LO(q1) * wdt2[2];                                          \
        xpv += SHUF_HI(q1) * wdt2[3];                                          \
        xpv += SHUF_LO(q2) * wdt2[4];                                          \
        xpv += SHUF_HI(q2) * wdt2[5];                                          \
        xpv += SHUF_LO(q3) * wdt2[6];                                          \
        xpv += SHUF_HI(q3) * wdt2[7];                                          \
        float xp = xpv.x + xpv.y;                                              \
        float ex = __expf(xp);                                                 \
        v4f r0 = *(const v4f*)&sdt[t][16];                                     \
        v4f r1 = *(const v4f*)&sdt[t][20];                                     \
        v4f r2 = *(const v4f*)&sdt[t][24];                                     \
        v4f r3 = *(const v4f*)&sdt[t][28];                                     \
        v2f bc[8];                                                             \
        bc[0] = SHUF_LO(r0); bc[1] = SHUF_HI(r0);                              \
        bc[2] = SHUF_LO(r1); bc[3] = SHUF_HI(r1);                              \
        bc[4] = SHUF_LO(r2); bc[5] = SHUF_HI(r2);                              \
        bc[6] = SHUF_LO(r3); bc[7] = SHUF_HI(r3);                              \
        v2f acc2 = {0.f, 0.f};                                                 \
        if (FASTV) {                                                           \
            float E = rcp_(1.f + ex);     /* exp(-softplus(xp)), v_rcp */      \
            v2f Ev; Ev.x = E; Ev.y = E * E;                                    \
            v2f Estep; Estep.x = Ev.y; Estep.y = Ev.y;                         \
            _Pragma("unroll")                                                  \
            for (int p = 0; p < 8; p++) {                                      \
                h2[p] = h2[p] * Ev + bc[p] * xv;                               \
                acc2 += h2[p];                                                 \
                Ev *= Estep;                                                   \
            }                                                                  \
            if (PASS == 1) ds *= E;       /* ds doubles as Eprod */            \
        } else {                                                               \
            float dtv = (xp > 15.f) ? xp : __logf(1.f + ex);                   \
            _Pragma("unroll")                                                  \
            for (int p = 0; p < 8; p++) {                                      \
                v2f es;                                                        \
                es.x = __expf(Ae2[p].x * dtv);                                 \
                es.y = __expf(Ae2[p].y * dtv);                                 \
                h2[p] = h2[p] * es + bc[p] * xv;                               \
                acc2 += h2[p];                                                 \
            }                                                                  \
            if (PASS == 1) ds += dtv;                                          \
        }                                                                      \
        if (PASS == 3) {                                                       \
            float accv = acc2.x + acc2.y;                                      \
            xcyz[ix] = f2bf(accv * zv * wd);  /* zv is pre-activated silu(z) */\
        }                                                                      \
        ix += 1024;                                                            \
        xv = xn;                                                               \
        zv = zn;                                                               \
    }

template <int PASS>
__global__ __launch_bounds__(256) void scan_chunk(const float* __restrict__ dtbc,
                                                  u16* __restrict__ xcyz,
                                                  const u16* __restrict__ zb,
                                                  const void* __restrict__ A_log,
                                                  const void* __restrict__ W_dt,
                                                  const void* __restrict__ b_dt,
                                                  const int* __restrict__ flags,
                                                  float* __restrict__ hend,
                                                  float* __restrict__ dtsum,
                                                  const void* __restrict__ dirw,
                                                  const int* __restrict__ perm3) {
    int fin = flags[0];
    int bid = blockIdx.x;
    int ec = bid & 3, c = (bid >> 2) & (NCHUNK - 1), b = (bid >> 6) & 7, d = bid >> 9;
    int e = ec * 256 + threadIdx.x;
    size_t row0 = (size_t)d * M1 + b * 1024 + c * CLEN;    // global A row
    size_t cix  = (size_t)d * (8 * NCHUNK) + b * NCHUNK + c;  // chunk index
    __shared__ float sdt[CLEN][32];
    __shared__ int s_perm[CLEN];
    {
        const float* src = dtbc + row0 * 64;
        for (int i = threadIdx.x; i < CLEN * 8; i += 256) {
            int t = i >> 3, f = i & 7;                     // CLEN rows x 8 f4
            *(float4*)&sdt[t][f * 4] = *(const float4*)(src + (size_t)t * 64 + f * 4);
        }
        if (PASS == 3 && threadIdx.x < CLEN)
            s_perm[threadIdx.x] = dirmap(d, c * CLEN + (int)threadIdx.x, perm3);
    }
    v2f Ae2[8], wdt2[8];
    bool fast = true;
#pragma unroll
    for (int p = 0; p < 8; p++) {
        float a0 = -__expf(ldf(A_log, (size_t)e * 16 + 2 * p, fin));
        float a1 = -__expf(ldf(A_log, (size_t)e * 16 + 2 * p + 1, fin));
        Ae2[p].x = a0;
        Ae2[p].y = a1;
        fast = fast && fabsf(a0 + (float)(2 * p + 1)) < 1e-3f * (2 * p + 1)
                    && fabsf(a1 + (float)(2 * p + 2)) < 1e-3f * (2 * p + 2);
    }
#pragma unroll
    for (int p = 0; p < 8; p++) {
        wdt2[p].x = ldf(W_dt, (size_t)(2 * p) * 1024 + e, fin);
        wdt2[p].y = ldf(W_dt, (size_t)(2 * p + 1) * 1024 + e, fin);
    }
    float bd = ldf(b_dt, e, fin);
    float wd = (PASS == 3) ? ldf(dirw, d, fin) : 0.f;
    v2f h2[8];
    if (PASS == 1) {
#pragma unroll
        for (int p = 0; p < 8; p++) h2[p] = (v2f){0.f, 0.f};
    } else {
#pragma unroll
        for (int p = 0; p < 8; p++) {
            h2[p].x = hend[(cix * 16 + 2 * p) * 1024 + e];
            h2[p].y = hend[(cix * 16 + 2 * p + 1) * 1024 + e];
        }
    }
    __syncthreads();
    float ds = fast ? 1.f : 0.f;       // Eprod (fast) or dt-sum (general)
    size_t ix = row0 * 1024 + e;
    size_t zbase = (size_t)b * 1024 * 1024 + e;
    float xv = bf2f(xcyz[ix]);                       // prefetch t=0
    float zv = (PASS == 3) ? bf2f(zb[zbase + (size_t)s_perm[0] * 1024]) : 0.f;
    if (fast) {
        SCAN_TLOOP(true)
    } else {
        SCAN_TLOOP(false)
    }
    if (PASS == 1) {
#pragma unroll
        for (int p = 0; p < 8; p++) {
            hend[(cix * 16 + 2 * p) * 1024 + e] = h2[p].x;
            hend[(cix * 16 + 2 * p + 1) * 1024 + e] = h2[p].y;
        }
        dtsum[cix * 1024 + e] = ds;
    }
}

// combine parallelized over (d, b, s, ec): 2048 blocks, each thread owns one
// (d,b,e,s) chain; sequential over c (NCHUNK=16 steps). Fast mode (same
// runtime A-check as scan_chunk): dtsum holds Eprod; decay = Eprod^(s+1) by
// binary exponentiation (no exp). General: exp(Ae*ds).
__global__ __launch_bounds__(256) void scan_combine2(float* __restrict__ hend,
                                                     const float* __restrict__ dtsum,
                                                     const void* __restrict__ A_log,
                                                     const int* __restrict__ flags) {
    int fin = flags[0];
    int bid = blockIdx.x;            // d*512 + b*64 + s*4 + ec
    int ec = bid & 3, s = (bid >> 2) & 15, b = (bid >> 6) & 7, d = bid >> 9;
    int e = ec * 256 + threadIdx.x;
    bool fast = true;
#pragma unroll
    for (int s2 = 0; s2 < 16; s2++) {
        float a = -__expf(ldf(A_log, (size_t)e * 16 + s2, fin));
        fast = fast && fabsf(a + (float)(s2 + 1)) < 1e-3f * (s2 + 1);
    }
    float Ae = -__expf(ldf(A_log, (size_t)e * 16 + s, fin));
    float H = 0.f;
    size_t base = (size_t)d * (8 * NCHUNK) + (size_t)b * NCHUNK;
    for (int c = 0; c < NCHUNK; c++) {
        size_t cix = base + c;
        float ds = dtsum[cix * 1024 + e];
        float decay;
        if (fast) {
            float r = 1.f, bb = ds;
            int n = s + 1;
            while (n) {
                if (n & 1) r *= bb;
                bb *= bb;
                n >>= 1;
            }
            decay = r;
        } else {
            decay = __expf(Ae * ds);
        }
        size_t idx = (cix * 16 + s) * 1024 + e;
        float loc = hend[idx];
        hend[idx] = H;
        H = loc + decay * H;
    }
}

// ---------------- LayerNorm with fused 4-direction gather-sum ---------------
// y4: 4 planes [d][b*1024+t][1024] bf16, direction order, dir_w pre-folded.
// Natural row (b,q) gathers t0=q, t1=1023-q, t2=transpose(q), t3=inv3[q].
__global__ __launch_bounds__(256) void ln4_kernel(const u16* __restrict__ y4,
                                                  const void* __restrict__ ln_g,
                                                  const void* __restrict__ ln_b,
                                                  const int* __restrict__ flags,
                                                  const int* __restrict__ inv3,
                                                  u16* __restrict__ fn) {
    int fin = flags[0];
    int row = blockIdx.x;            // b*1024 + q
    int b = row >> 10, q = row & 1023;
    int t1 = 1023 - q;
    int t2 = ((q & 31) << 5) | (q >> 5);
    int t3 = inv3[q];
    const u16* p0 = y4 + ((size_t)(b * 1024 + q)) * 1024;
    const u16* p1 = y4 + ((size_t)(M1 + b * 1024 + t1)) * 1024;
    const u16* p2 = y4 + ((size_t)(2 * M1 + b * 1024 + t2)) * 1024;
    const u16* p3 = y4 + ((size_t)(3 * M1 + b * 1024 + t3)) * 1024;
    int e0 = threadIdx.x * 4;
    uint2 a0 = *(const uint2*)(p0 + e0);
    uint2 a1 = *(const uint2*)(p1 + e0);
    uint2 a2 = *(const uint2*)(p2 + e0);
    uint2 a3 = *(const uint2*)(p3 + e0);
    const u16* s0 = (const u16*)&a0;
    const u16* s1 = (const u16*)&a1;
    const u16* s2 = (const u16*)&a2;
    const u16* s3 = (const u16*)&a3;
    float v[4];
    float sum = 0.f, sq = 0.f;
#pragma unroll
    for (int j = 0; j < 4; j++) {
        float f = bf2f(s0[j]) + bf2f(s1[j]) + bf2f(s2[j]) + bf2f(s3[j]);
        v[j] = f;
        sum += f;
        sq += f * f;
    }
    __shared__ float r1[256], r2[256];
    r1[threadIdx.x] = sum;
    r2[threadIdx.x] = sq;
    __syncthreads();
    for (int s = 128; s > 0; s >>= 1) {
        if (threadIdx.x < s) {
            r1[threadIdx.x] += r1[threadIdx.x + s];
            r2[threadIdx.x] += r2[threadIdx.x + s];
        }
        __syncthreads();
    }
    float mu = r1[0] * (1.f / 1024.f);
    float var = r2[0] * (1.f / 1024.f) - mu * mu;
    float rs = rsqrtf(var + 1e-5f);
    u16 o[4];
#pragma unroll
    for (int j = 0; j < 4; j++) {
        int e = e0 + j;
        o[j] = f2bf((v[j] - mu) * rs * ldf(ln_g, e, fin) + ldf(ln_b, e, fin));
    }
    *(uint2*)(fn + (size_t)row * 1024 + e0) = *(const uint2*)o;
}

// ---------------- gate: partial col sums -> shared matvec -> finisher -------
__global__ __launch_bounds__(256) void gate_partial(const u16* __restrict__ vfb,
                                                    float* __restrict__ meanv) {
    int b = blockIdx.x >> 4, tc = blockIdx.x & 15;
    float s[4] = {0.f, 0.f, 0.f, 0.f};
    const u16* base = vfb + ((size_t)b * 1024 + tc * 64) * 1024;
    for (int t = 0; t < 64; t++) {
#pragma unroll
        for (int k = 0; k < 4; k++)
            s[k] += bf2f(base[(size_t)t * 1024 + threadIdx.x + k * 256]);
    }
#pragma unroll
    for (int k = 0; k < 4; k++)
        atomicAdd(&meanv[b * 1024 + threadIdx.x + k * 256], s[k]);
}

__global__ __launch_bounds__(256) void gate_mv(const float* __restrict__ meanv,
                                               const void* __restrict__ Wg1,
                                               const int* __restrict__ flags,
                                               float* __restrict__ gpart) {
    int fin = flags[0];
    int kc = blockIdx.x, j = threadIdx.x;
    __shared__ float mv[8][32];
    if (threadIdx.x < 8 * 32) {
        int b = threadIdx.x >> 5, kk = threadIdx.x & 31;
        mv[b][kk] = meanv[b * 1024 + kc * 32 + kk] * (1.f / 1024.f);
    }
    __syncthreads();
    float acc[8];
#pragma unroll
    for (int b = 0; b < 8; b++) acc[b] = 0.f;
    for (int kk = 0; kk < 32; kk++) {
        float w = ldf(Wg1, (size_t)(kc * 32 + kk) * 256 + j, fin);
#pragma unroll
        for (int b = 0; b < 8; b++) acc[b] += mv[b][kk] * w;
    }
#pragma unroll
    for (int b = 0; b < 8; b++) atomicAdd(&gpart[b * 256 + j], acc[b]);
}

__global__ __launch_bounds__(256) void gate_fin2(const float* __restrict__ gpart,
                                                 const void* __restrict__ Wg2,
                                                 const int* __restrict__ flags,
                                                 float* __restrict__ g) {
    int fin = flags[0];
    int b = blockIdx.x, j = threadIdx.x;
    __shared__ float red[256];
    float a = gpart[b * 256 + j];
    float si = a * sigmoidf_(a);
    red[j] = si * ldf(Wg2, j, fin);
    __syncthreads();
    for (int st = 128; st > 0; st >>= 1) {
        if (j < st) red[j] += red[j + st];
        __syncthreads();
    }
    if (j == 0) g[b] = sigmoidf_(red[0]);
}

// ---------------- launch ----------------------------------------------------
extern "C" void kernel_launch(void* const* d_in, const int* in_sizes, int n_in,
                              void* d_out, int out_size, void* d_ws, size_t ws_size,
                              hipStream_t stream) {
    const void* vf_raw  = d_in[0];
    const void* W_input = d_in[1];
    const void* W_in    = d_in[2];
    const void* conv_w  = d_in[3];
    const void* W_xproj = d_in[4];
    const void* W_dt    = d_in[5];
    const void* b_dt    = d_in[6];
    const void* A_log   = d_in[7];
    const void* W_outm  = d_in[8];
    const void* dir_w   = d_in[9];
    const void* ln_g    = d_in[10];
    const void* ln_b    = d_in[11];
    const void* W_outpj = d_in[12];
    const void* Wg1     = d_in[13];
    const void* Wg2     = d_in[14];

    char* ws = (char*)d_ws;
    size_t off = 0;
    auto alloc = [&](size_t bytes) -> void* {
        void* p = ws + off;
        off = (off + bytes + 255) & ~(size_t)255;
        return p;
    };
    int*   flags = (int*)alloc(256);
    int*   perm3 = (int*)alloc(NN * 4);
    int*   inv3  = (int*)alloc(NN * 4);
    float* meanv = (float*)alloc(8 * 1024 * 4);
    float* gpart = (float*)alloc(8 * 256 * 4);   // contiguous after meanv
    float* gbuf  = (float*)alloc(64);
    u16*   WiB   = (u16*)alloc((size_t)1024 * 1024 * 2);   // W_input bf16 (Bt fmt)
    u16*   WtIn  = (u16*)alloc((size_t)2048 * 1024 * 2);
    u16*   WtF   = (u16*)alloc((size_t)2048 * 1024 * 2);   // fused (W_in^T@W_input^T)
    u16*   WtXp  = (u16*)alloc((size_t)64 * 1024 * 2);
    u16*   WtOm  = (u16*)alloc((size_t)1024 * 1024 * 2);
    u16*   WtOp  = (u16*)alloc((size_t)1024 * 1024 * 2);
    // --- 64 MiB region reused over the pipeline lifetime:
    //     (1) vfb(16M)+xbuf(16M) early (convert/gate/EM1);
    //     (2) hend4 = 32 MiB during the scans;
    //     (3) y4 = 4 bf16 direction-planes (64 MiB) for EM3-seq -> ln4.
    u16*   vfb   = (u16*)alloc((size_t)M1 * 1024 * 2);
    u16*   xbuf  = (u16*)alloc((size_t)M1 * 1024 * 2);    // (dead; alias filler)
    float* tail32= (float*)alloc((size_t)M1 * 1024 * 4);  // completes the 64 MiB
    u16*   xi    = (u16*)alloc((size_t)M1 * 1024 * 2);   // later: fn
    u16*   zb    = (u16*)alloc((size_t)M1 * 1024 * 2);
    u16*   xc4   = (u16*)alloc((size_t)M4 * 1024 * 2);   // 4 dir-planes, 64 MiB
    float* dtbc4 = (float*)alloc((size_t)M4 * 64 * 4);   // 8 MiB
    float* dtsum4= (float*)alloc((size_t)4 * 8 * NCHUNK * 1024 * 4);  // 2 MiB
    float* hend4 = (float*)vfb;
    u16*   y4    = (u16*)vfb;
    (void)tail32;
    (void)xbuf;

    setup_kernel<<<4, 256, 0, stream>>>((const u16*)vf_raw, flags, perm3, inv3);
    convert_bf<<<(M1 * 1024) / 256, 256, 0, stream>>>(vf_raw, vfb, flags, M1 * 1024);
    // W_input: plain bf16 convert (native row-major IS the Bt layout needed below)
    convert_bf<<<(1024 * 1024) / 256, 256, 0, stream>>>(W_input, WiB, flags, 1024 * 1024);
    // all four weight transposes in one dispatch
    transpose_pad4<<<dim3(32, 130), 256, 0, stream>>>(
        W_in, WtIn, W_xproj, WtXp, W_outm, WtOm, W_outpj, WtOp, flags);
    // meanv + gpart are contiguous: one zero-fill
    zero_f32<<<40, 256, 0, stream>>>(meanv, 8 * 1024 + 8 * 256);

    // Fused weight: WtF[m][k] = sum_j W_in[j][m] * W_input[k][j]
    //             = (W_input @ W_in)^T  — exactly the Bt layout for stage 2.
    // Small (6 MB, L2-resident) -> 64x64 tiles for grid occupancy (512 blocks).
    gemm128<0, 2, 2><<<dim3(32, 16), 256, 0, stream>>>(
        WtIn, WiB, WtF, nullptr, 2048, 1024, 1024, flags, nullptr, nullptr);

    // gate (uses vfb before hend4 aliases it — stream-ordered)
    gate_partial<<<128, 256, 0, stream>>>(vfb, meanv);
    gate_mv<<<32, 256, 0, stream>>>(meanv, Wg1, flags, gpart);
    gate_fin2<<<8, 256, 0, stream>>>(gpart, Wg2, flags, gbuf);

    // stage 1+2 fused: xz = vf @ (W_input @ W_in) -> xi, silu(z)
    gemm128<1, 4, 4><<<dim3(64, 16), 256, 0, stream>>>(
        vfb, WtF, xi, zb, M1, 2048, 1024, flags, nullptr, nullptr);

    // ---- all four directions batched (independent given xi, zb) ----
    conv_tile<<<4096, 256, 0, stream>>>(xi, conv_w, xc4, flags, perm3);
    // dtbc via the BK=64 GEMM template (EM=5 fp32 store): 64x64 tiles, (512,1)
    gemm128<5, 2, 2><<<dim3(512, 1), 256, 0, stream>>>(
        xc4, WtXp, dtbc4, nullptr, M4, 64, 1024, flags, nullptr, nullptr);
    scan_chunk<1><<<2048, 256, 0, stream>>>(dtbc4, xc4, zb, A_log, W_dt, b_dt,
                                            flags, hend4, dtsum4, dir_w, perm3);
    scan_combine2<<<2048, 256, 0, stream>>>(hend4, dtsum4, A_log, flags);
    scan_chunk<3><<<2048, 256, 0, stream>>>(dtbc4, xc4, zb, A_log, W_dt, b_dt,
                                            flags, hend4, dtsum4, dir_w, perm3);

    // hend4 dead -> y4 reuses the same 64 MiB. One fused plain-store GEMM:
    // y4[d] = (w_d * y_d) @ W_outm, 128x128 tiles (2048 blocks).
    gemm128<0, 4, 4><<<dim3(256, 8), 256, 0, stream>>>(
        xc4, WtOm, y4, nullptr, M4, 1024, 1024, flags, nullptr, nullptr);

    // LayerNorm fused with the 4-direction gather-sum (row-granular gathers).
    u16* fn = xi;  // xi dead after conv
    ln4_kernel<<<M1, 256, 0, stream>>>(y4, ln_g, ln_b, flags, inv3, fn);
    gemm128<4, 4, 4><<<dim3(64, 8), 256, 0, stream>>>(
        fn, WtOp, d_out, nullptr, M1, 1024, 1024, flags, vf_raw, gbuf);
}